// Round 2
// baseline (284.000 us; speedup 1.0000x reference)
//
#include <hip/hip_runtime.h>

#define D_FEAT 32
#define SCAN_BLOCK 1024

// ---------- CSR-build path ----------

__global__ void hist_kernel(const int* __restrict__ dst, unsigned* __restrict__ deg, int E) {
    int i = blockIdx.x * blockDim.x + threadIdx.x;
    int stride = gridDim.x * blockDim.x;
    for (; i < E; i += stride) atomicAdd(&deg[dst[i]], 1u);
}

// per-block inclusive scan (Hillis-Steele), writes partials + block sums
__global__ void scan1_kernel(const unsigned* __restrict__ deg, unsigned* __restrict__ partial,
                             unsigned* __restrict__ blocksum, int N) {
    __shared__ unsigned tmp[SCAN_BLOCK];
    int tid = threadIdx.x;
    int gid = blockIdx.x * SCAN_BLOCK + tid;
    unsigned v = (gid < N) ? deg[gid] : 0u;
    tmp[tid] = v;
    for (int off = 1; off < SCAN_BLOCK; off <<= 1) {
        __syncthreads();
        unsigned t = (tid >= off) ? tmp[tid - off] : 0u;
        __syncthreads();
        tmp[tid] += t;
    }
    if (gid < N) partial[gid] = tmp[tid];
    if (tid == SCAN_BLOCK - 1) blocksum[blockIdx.x] = tmp[tid];
}

// single-block exclusive scan of block sums (nb <= 1024)
__global__ void scan2_kernel(const unsigned* __restrict__ blocksum, unsigned* __restrict__ blockoff, int nb) {
    __shared__ unsigned tmp[SCAN_BLOCK];
    int tid = threadIdx.x;
    unsigned v = (tid < nb) ? blocksum[tid] : 0u;
    tmp[tid] = v;
    for (int off = 1; off < SCAN_BLOCK; off <<= 1) {
        __syncthreads();
        unsigned t = (tid >= off) ? tmp[tid - off] : 0u;
        __syncthreads();
        tmp[tid] += t;
    }
    if (tid < nb) blockoff[tid] = tmp[tid] - v;  // exclusive
}

// rowstart = exclusive scan; cursor = rowstart copy; inv = rsqrt(1+deg)
__global__ void scan3_kernel(const unsigned* __restrict__ deg, const unsigned* __restrict__ partial,
                             const unsigned* __restrict__ blockoff,
                             unsigned* __restrict__ rowstart, unsigned* __restrict__ cursor,
                             float* __restrict__ inv, int N) {
    int i = blockIdx.x * blockDim.x + threadIdx.x;
    if (i >= N) return;
    unsigned d = deg[i];
    unsigned start = partial[i] - d + blockoff[i >> 10];  // SCAN_BLOCK == 1024
    rowstart[i] = start;
    cursor[i] = start;
    inv[i] = rsqrtf(1.0f + (float)d);
}

__global__ void fill_kernel(const int* __restrict__ src, const int* __restrict__ dst,
                            unsigned* __restrict__ cursor, unsigned* __restrict__ csr, int E) {
    int i = blockIdx.x * blockDim.x + threadIdx.x;
    int stride = gridDim.x * blockDim.x;
    for (; i < E; i += stride) {
        unsigned pos = atomicAdd(&cursor[dst[i]], 1u);
        csr[pos] = (unsigned)src[i];
    }
}

// one wave (64 lanes) per node: 2 neighbors x 32 dims per iteration, register accumulate,
// shfl-reduce across halves, single coalesced 128B write. Self-loop fused.
__global__ void gather_kernel(const float* __restrict__ feat, const unsigned* __restrict__ csr,
                              const unsigned* __restrict__ rowstart, const unsigned* __restrict__ deg,
                              const float* __restrict__ inv, float* __restrict__ out, int N) {
    int wid = threadIdx.x >> 6;
    int lane = threadIdx.x & 63;
    int node = blockIdx.x * (blockDim.x >> 6) + wid;
    if (node >= N) return;
    int h = lane >> 5;   // which half-wave
    int d = lane & 31;   // feature dim
    unsigned start = rowstart[node];
    unsigned dg = deg[node];
    float iv = inv[node];
    // self-loop contribution: inv[i]*feat[i][d] (times iv at the end -> iv^2 * feat)
    float acc = (h == 0) ? iv * feat[(size_t)node * D_FEAT + d] : 0.0f;
    for (unsigned k = h; k < dg; k += 2) {
        unsigned j = csr[start + k];
        acc += inv[j] * feat[(size_t)j * D_FEAT + d];
    }
    acc += __shfl_xor(acc, 32);
    if (h == 0) out[(size_t)node * D_FEAT + d] = iv * acc;
}

// ---------- fallback (round-1 path) if workspace is too small ----------

__global__ void fb_deg_kernel(const int* __restrict__ dst, float* __restrict__ deg, int E) {
    int i = blockIdx.x * blockDim.x + threadIdx.x;
    int stride = gridDim.x * blockDim.x;
    for (; i < E; i += stride) atomicAdd(&deg[dst[i]], 1.0f);
}
__global__ void fb_inv_kernel(const float* __restrict__ deg, float* __restrict__ inv, int N) {
    int i = blockIdx.x * blockDim.x + threadIdx.x;
    if (i < N) inv[i] = rsqrtf(1.0f + deg[i]);
}
__global__ void fb_scatter_kernel(const float* __restrict__ feat, const int* __restrict__ src,
                                  const int* __restrict__ dst, const float* __restrict__ inv,
                                  float* __restrict__ out, int E) {
    long long tid = (long long)blockIdx.x * blockDim.x + threadIdx.x;
    int e = (int)(tid >> 5);
    int d = (int)(tid & 31);
    if (e >= E) return;
    int s = src[e];
    int t = dst[e];
    atomicAdd(&out[t * D_FEAT + d], inv[s] * feat[s * D_FEAT + d]);
}
__global__ void fb_finalize_kernel(const float* __restrict__ feat, const float* __restrict__ inv,
                                   float* __restrict__ out, int ND) {
    int tid = blockIdx.x * blockDim.x + threadIdx.x;
    if (tid >= ND) return;
    float iv = inv[tid >> 5];
    out[tid] = iv * (out[tid] + iv * feat[tid]);
}

extern "C" void kernel_launch(void* const* d_in, const int* in_sizes, int n_in,
                              void* d_out, int out_size, void* d_ws, size_t ws_size,
                              hipStream_t stream) {
    const float* feat = (const float*)d_in[0];
    const int* esrc = (const int*)d_in[1];
    const int* edst = (const int*)d_in[2];
    float* out = (float*)d_out;

    const int N = in_sizes[0] / D_FEAT;
    const int E = in_sizes[1];
    const int ND = N * D_FEAT;
    const int nblocks = (N + SCAN_BLOCK - 1) / SCAN_BLOCK;

    // workspace layout (all 4-byte elems)
    size_t need = (size_t)(5 * N + 2 * SCAN_BLOCK + E) * 4;
    if (ws_size >= need && nblocks <= SCAN_BLOCK) {
        unsigned* deg      = (unsigned*)d_ws;       // N
        unsigned* rowstart = deg + N;               // N (holds partial, then rowstart in-place style)
        unsigned* cursor   = rowstart + N;          // N
        float*    inv      = (float*)(cursor + N);  // N
        unsigned* blocksum = (unsigned*)(inv + N);  // SCAN_BLOCK
        unsigned* blockoff = blocksum + SCAN_BLOCK; // SCAN_BLOCK
        unsigned* csr      = blockoff + SCAN_BLOCK; // E

        hipMemsetAsync(deg, 0, (size_t)N * sizeof(unsigned), stream);

        {
            int grid = (E + 255) / 256; if (grid > 2048) grid = 2048;
            hist_kernel<<<grid, 256, 0, stream>>>(edst, deg, E);
        }
        scan1_kernel<<<nblocks, SCAN_BLOCK, 0, stream>>>(deg, rowstart, blocksum, N);
        scan2_kernel<<<1, SCAN_BLOCK, 0, stream>>>(blocksum, blockoff, nblocks);
        scan3_kernel<<<(N + 255) / 256, 256, 0, stream>>>(deg, rowstart, blockoff,
                                                          rowstart, cursor, inv, N);
        {
            int grid = (E + 255) / 256; if (grid > 4096) grid = 4096;
            fill_kernel<<<grid, 256, 0, stream>>>(esrc, edst, cursor, csr, E);
        }
        {
            int waves_per_block = 4;  // 256 threads
            int grid = (N + waves_per_block - 1) / waves_per_block;
            gather_kernel<<<grid, 256, 0, stream>>>(feat, csr, rowstart, deg, inv, out, N);
        }
    } else {
        // fallback: atomic scatter path
        float* deg = (float*)d_ws;
        float* inv = deg + N;
        hipMemsetAsync(deg, 0, (size_t)N * sizeof(float), stream);
        hipMemsetAsync(out, 0, (size_t)ND * sizeof(float), stream);
        {
            int grid = (E + 255) / 256; if (grid > 2048) grid = 2048;
            fb_deg_kernel<<<grid, 256, 0, stream>>>(edst, deg, E);
        }
        fb_inv_kernel<<<(N + 255) / 256, 256, 0, stream>>>(deg, inv, N);
        {
            long long total = (long long)E * D_FEAT;
            fb_scatter_kernel<<<(int)((total + 255) / 256), 256, 0, stream>>>(feat, esrc, edst, inv, out, E);
        }
        fb_finalize_kernel<<<(ND + 255) / 256, 256, 0, stream>>>(feat, inv, out, ND);
    }
}

// Round 3
// 173.468 us; speedup vs baseline: 1.6372x; 1.6372x over previous
//
#include <hip/hip_runtime.h>

#define D_FEAT 32
#define SCAN_BLOCK 1024

// ---------- CSR-build path (atomic rank capture) ----------

// deg[dst]++ with returned rank per edge. 4 edges/thread via int4.
__global__ void hist_rank_kernel(const int* __restrict__ dst, unsigned* __restrict__ deg,
                                 unsigned* __restrict__ rank, int E) {
    int i4 = blockIdx.x * blockDim.x + threadIdx.x;
    int stride = gridDim.x * blockDim.x;
    int nq = E >> 2;
    for (int q = i4; q < nq; q += stride) {
        int4 d4 = ((const int4*)dst)[q];
        uint4 r;
        r.x = atomicAdd(&deg[d4.x], 1u);
        r.y = atomicAdd(&deg[d4.y], 1u);
        r.z = atomicAdd(&deg[d4.z], 1u);
        r.w = atomicAdd(&deg[d4.w], 1u);
        ((uint4*)rank)[q] = r;
    }
    // tail
    for (int i = (nq << 2) + i4; i < E; i += stride)
        rank[i] = atomicAdd(&deg[dst[i]], 1u);
}

// per-block inclusive scan
__global__ void scan1_kernel(const unsigned* __restrict__ deg, unsigned* __restrict__ partial,
                             unsigned* __restrict__ blocksum, int N) {
    __shared__ unsigned tmp[SCAN_BLOCK];
    int tid = threadIdx.x;
    int gid = blockIdx.x * SCAN_BLOCK + tid;
    unsigned v = (gid < N) ? deg[gid] : 0u;
    tmp[tid] = v;
    for (int off = 1; off < SCAN_BLOCK; off <<= 1) {
        __syncthreads();
        unsigned t = (tid >= off) ? tmp[tid - off] : 0u;
        __syncthreads();
        tmp[tid] += t;
    }
    if (gid < N) partial[gid] = tmp[tid];
    if (tid == SCAN_BLOCK - 1) blocksum[blockIdx.x] = tmp[tid];
}

// single-block exclusive scan of block sums
__global__ void scan2_kernel(const unsigned* __restrict__ blocksum, unsigned* __restrict__ blockoff, int nb) {
    __shared__ unsigned tmp[SCAN_BLOCK];
    int tid = threadIdx.x;
    unsigned v = (tid < nb) ? blocksum[tid] : 0u;
    tmp[tid] = v;
    for (int off = 1; off < SCAN_BLOCK; off <<= 1) {
        __syncthreads();
        unsigned t = (tid >= off) ? tmp[tid - off] : 0u;
        __syncthreads();
        tmp[tid] += t;
    }
    if (tid < nb) blockoff[tid] = tmp[tid] - v;  // exclusive
}

// rowstart = exclusive scan; inv = rsqrt(1+deg)
__global__ void scan3_kernel(const unsigned* __restrict__ deg, const unsigned* __restrict__ partial,
                             const unsigned* __restrict__ blockoff,
                             unsigned* __restrict__ rowstart, float* __restrict__ inv, int N) {
    int i = blockIdx.x * blockDim.x + threadIdx.x;
    if (i >= N) return;
    unsigned d = deg[i];
    rowstart[i] = partial[i] - d + blockoff[i >> 10];
    inv[i] = rsqrtf(1.0f + (float)d);
}

// atomic-free fill: csr[rowstart[dst]+rank] = {src, inv[src]}
__global__ void fill_kernel(const int* __restrict__ src, const int* __restrict__ dst,
                            const unsigned* __restrict__ rank, const unsigned* __restrict__ rowstart,
                            const float* __restrict__ inv, uint2* __restrict__ csr, int E) {
    int i4 = blockIdx.x * blockDim.x + threadIdx.x;
    int stride = gridDim.x * blockDim.x;
    int nq = E >> 2;
    for (int q = i4; q < nq; q += stride) {
        int4 s4 = ((const int4*)src)[q];
        int4 d4 = ((const int4*)dst)[q];
        uint4 r4 = ((const uint4*)rank)[q];
        csr[rowstart[d4.x] + r4.x] = make_uint2((unsigned)s4.x, __float_as_uint(inv[s4.x]));
        csr[rowstart[d4.y] + r4.y] = make_uint2((unsigned)s4.y, __float_as_uint(inv[s4.y]));
        csr[rowstart[d4.z] + r4.z] = make_uint2((unsigned)s4.z, __float_as_uint(inv[s4.z]));
        csr[rowstart[d4.w] + r4.w] = make_uint2((unsigned)s4.w, __float_as_uint(inv[s4.w]));
    }
    for (int i = (nq << 2) + i4; i < E; i += stride) {
        int s = src[i];
        csr[rowstart[dst[i]] + rank[i]] = make_uint2((unsigned)s, __float_as_uint(inv[s]));
    }
}

// one wave per node: 2 neighbors x 32 dims per iter, 2-way unrolled, register accumulate.
__global__ void gather_kernel(const float* __restrict__ feat, const uint2* __restrict__ csr,
                              const unsigned* __restrict__ rowstart, const unsigned* __restrict__ deg,
                              const float* __restrict__ inv, float* __restrict__ out, int N) {
    int wid = threadIdx.x >> 6;
    int lane = threadIdx.x & 63;
    int node = blockIdx.x * (blockDim.x >> 6) + wid;
    if (node >= N) return;
    int h = lane >> 5;   // half-wave id
    int d = lane & 31;   // feature dim
    unsigned start = rowstart[node];
    unsigned dg = deg[node];
    float iv = inv[node];
    float acc = (h == 0) ? iv * feat[(size_t)node * D_FEAT + d] : 0.0f;  // self-loop
    unsigned k = h;
    for (; k + 2 < dg; k += 4) {
        uint2 e1 = csr[start + k];
        uint2 e2 = csr[start + k + 2];
        acc += __uint_as_float(e1.y) * feat[(size_t)e1.x * D_FEAT + d];
        acc += __uint_as_float(e2.y) * feat[(size_t)e2.x * D_FEAT + d];
    }
    for (; k < dg; k += 2) {
        uint2 e = csr[start + k];
        acc += __uint_as_float(e.y) * feat[(size_t)e.x * D_FEAT + d];
    }
    acc += __shfl_xor(acc, 32);
    if (h == 0) out[(size_t)node * D_FEAT + d] = iv * acc;
}

// ---------- fallback (atomic scatter) if workspace too small ----------

__global__ void fb_deg_kernel(const int* __restrict__ dst, float* __restrict__ deg, int E) {
    int i = blockIdx.x * blockDim.x + threadIdx.x;
    int stride = gridDim.x * blockDim.x;
    for (; i < E; i += stride) atomicAdd(&deg[dst[i]], 1.0f);
}
__global__ void fb_inv_kernel(const float* __restrict__ deg, float* __restrict__ inv, int N) {
    int i = blockIdx.x * blockDim.x + threadIdx.x;
    if (i < N) inv[i] = rsqrtf(1.0f + deg[i]);
}
__global__ void fb_scatter_kernel(const float* __restrict__ feat, const int* __restrict__ src,
                                  const int* __restrict__ dst, const float* __restrict__ inv,
                                  float* __restrict__ out, int E) {
    long long tid = (long long)blockIdx.x * blockDim.x + threadIdx.x;
    int e = (int)(tid >> 5);
    int d = (int)(tid & 31);
    if (e >= E) return;
    int s = src[e];
    int t = dst[e];
    atomicAdd(&out[t * D_FEAT + d], inv[s] * feat[s * D_FEAT + d]);
}
__global__ void fb_finalize_kernel(const float* __restrict__ feat, const float* __restrict__ inv,
                                   float* __restrict__ out, int ND) {
    int tid = blockIdx.x * blockDim.x + threadIdx.x;
    if (tid >= ND) return;
    float iv = inv[tid >> 5];
    out[tid] = iv * (out[tid] + iv * feat[tid]);
}

extern "C" void kernel_launch(void* const* d_in, const int* in_sizes, int n_in,
                              void* d_out, int out_size, void* d_ws, size_t ws_size,
                              hipStream_t stream) {
    const float* feat = (const float*)d_in[0];
    const int* esrc = (const int*)d_in[1];
    const int* edst = (const int*)d_in[2];
    float* out = (float*)d_out;

    const int N = in_sizes[0] / D_FEAT;
    const int E = in_sizes[1];
    const int ND = N * D_FEAT;
    const int nblocks = (N + SCAN_BLOCK - 1) / SCAN_BLOCK;

    // workspace words: csr(2E) + deg(N) + rank(E) + rowstart(N) + inv(N) + 2*SCAN_BLOCK
    size_t need = ((size_t)3 * E + 3 * (size_t)N + 2 * SCAN_BLOCK) * 4;
    if (ws_size >= need && nblocks <= SCAN_BLOCK) {
        uint2*    csr      = (uint2*)d_ws;              // 2E words (8B aligned at base)
        unsigned* deg      = (unsigned*)(csr + E);      // N
        unsigned* rank     = deg + N;                   // E
        unsigned* rowstart = rank + E;                  // N
        float*    inv      = (float*)(rowstart + N);    // N
        unsigned* blocksum = (unsigned*)(inv + N);      // SCAN_BLOCK
        unsigned* blockoff = blocksum + SCAN_BLOCK;     // SCAN_BLOCK

        hipMemsetAsync(deg, 0, (size_t)N * sizeof(unsigned), stream);

        {
            int grid = ((E >> 2) + 255) / 256; if (grid > 2048) grid = 2048;
            hist_rank_kernel<<<grid, 256, 0, stream>>>(edst, deg, rank, E);
        }
        scan1_kernel<<<nblocks, SCAN_BLOCK, 0, stream>>>(deg, rowstart, blocksum, N);
        scan2_kernel<<<1, SCAN_BLOCK, 0, stream>>>(blocksum, blockoff, nblocks);
        scan3_kernel<<<(N + 255) / 256, 256, 0, stream>>>(deg, rowstart, blockoff, rowstart, inv, N);
        {
            int grid = ((E >> 2) + 255) / 256; if (grid > 2048) grid = 2048;
            fill_kernel<<<grid, 256, 0, stream>>>(esrc, edst, rank, rowstart, inv, csr, E);
        }
        {
            int waves_per_block = 4;  // 256 threads
            int grid = (N + waves_per_block - 1) / waves_per_block;
            gather_kernel<<<grid, 256, 0, stream>>>(feat, csr, rowstart, deg, inv, out, N);
        }
    } else {
        float* deg = (float*)d_ws;
        float* inv = deg + N;
        hipMemsetAsync(deg, 0, (size_t)N * sizeof(float), stream);
        hipMemsetAsync(out, 0, (size_t)ND * sizeof(float), stream);
        {
            int grid = (E + 255) / 256; if (grid > 2048) grid = 2048;
            fb_deg_kernel<<<grid, 256, 0, stream>>>(edst, deg, E);
        }
        fb_inv_kernel<<<(N + 255) / 256, 256, 0, stream>>>(deg, inv, N);
        {
            long long total = (long long)E * D_FEAT;
            fb_scatter_kernel<<<(int)((total + 255) / 256), 256, 0, stream>>>(feat, esrc, edst, inv, out, E);
        }
        fb_finalize_kernel<<<(ND + 255) / 256, 256, 0, stream>>>(feat, inv, out, ND);
    }
}